// Round 6
// baseline (561.733 us; speedup 1.0000x reference)
//
#include <hip/hip_runtime.h>
#include <hip/hip_fp16.h>
#include <stdint.h>

// VGAE GCN encoder. CSR build via LDS-binned 2-phase bucket partition:
//   k_part: edges -> 782 buckets (128 dst-nodes each); LDS rings, 64B flushes.
//   k_bscan: 782-entry exclusive scan -> bucket bases; offs[N]=E.
//   k_p2: rank captured from count-pass atomicAdd (pass 2 atomic-free).
// k_gemm1m (R6): h1s = dinv*(x@W1), mfma 16x16x32 f16. 4 named A-buffers
//   (P/Q/R/S), A-loads issued 2 STEPS ahead (~450cyc slack x3 waves/SIMD > 900cyc
//   HBM latency); W 2-buffered (L2). R4's 1-step-ahead left ~220cyc slack ->
//   latency-bound at ~90us vs 33us stream floor (R1->R5 delta accounting).
// All activations PRESCALED by dinv: pulls are pure row sums.
// pull64 (R6): csr loads software-pipelined one 16-edge group ahead (breaks the
//   serial 200cyc csr -> 450cyc gather chain); self-loop gather issued first.

#define BSHIFT 7
#define BPB 128           // nodes per bucket
#define CAP 5632          // slots per bucket in pairs (avg 4096 + 24 sigma)
#define NBMAX 800         // >= NB = 782
#define CAPB 40           // LDS ring slots per bin

typedef _Float16 f16x8 __attribute__((ext_vector_type(8)));
typedef float f32x4 __attribute__((ext_vector_type(4)));

// ---------------- partition: edges -> bucketed pairs ----------------
__global__ __launch_bounds__(1024) void k_part(const int* __restrict__ esrc, const int* __restrict__ edst,
                                               int* __restrict__ bcnt, int* __restrict__ pairs,
                                               int E, int NB, int nblocks) {
  __shared__ int bincnt[NBMAX];
  __shared__ int sflushed[NBMAX];
  __shared__ int binbuf[NBMAX * CAPB];
  const int tid = threadIdx.x;
  for (int b = tid; b < NB; b += 1024) { bincnt[b] = 0; sflushed[b] = 0; }
  __syncthreads();
  const int chunk = (E + nblocks - 1) / nblocks;
  const int e0 = blockIdx.x * chunk;
  const int e1 = min(e0 + chunk, E);
  for (int base = e0; base < e1; base += 1024) {
    int e = base + tid;
    if (e < e1) {
      int d = edst[e], s = esrc[e];
      int b = d >> BSHIFT;
      int pos = atomicAdd(&bincnt[b], 1);
      binbuf[b * CAPB + (pos % CAPB)] = (s << BSHIFT) | (d & (BPB - 1));
    }
    __syncthreads();
    if (tid < NB) {
      int c = bincnt[tid], f = sflushed[tid];
      while (c - f >= 16) {  // flush full 64B lines only
        int p = atomicAdd(&bcnt[tid * 16], 16);
#pragma unroll
        for (int j = 0; j < 16; ++j)
          pairs[(size_t)tid * CAP + p + j] = binbuf[tid * CAPB + ((f + j) % CAPB)];
        f += 16;
      }
      sflushed[tid] = f;
    }
    __syncthreads();
  }
  if (tid < NB) {  // drain partial lines (<=1 per bin per block)
    int c = bincnt[tid], f = sflushed[tid];
    int rem = c - f;
    if (rem > 0) {
      int p = atomicAdd(&bcnt[tid * 16], rem);
      for (int j = 0; j < rem; ++j)
        pairs[(size_t)tid * CAP + p + j] = binbuf[tid * CAPB + ((f + j) % CAPB)];
    }
  }
}

// ---------------- W1 -> fp16 B-fragment layout ----------------
// wf[(s*4 + t)*64 + l][j] = W[s*32 + (l>>4)*8 + j][t*16 + (l&15)]
__global__ __launch_bounds__(256) void k_wprep(const float* __restrict__ W, _Float16* __restrict__ wf) {
  int idx = blockIdx.x * 256 + threadIdx.x;  // 0..4095
  int l = idx & 63, st = idx >> 6;
  int t = st & 3, s = st >> 2;
  int kg = l >> 4, c = l & 15;
  f16x8 v;
#pragma unroll
  for (int j = 0; j < 8; ++j)
    v[j] = (_Float16)W[(size_t)(s * 32 + kg * 8 + j) * 64 + t * 16 + c];
  *(f16x8*)(wf + (size_t)idx * 8) = v;
}

// ---------------- GEMM1 (MFMA): h1s[n][64] = dinv*(x[n][512] @ W1[512][64]) ----
// 4 named A-buffers (2-step-ahead HBM prefetch), 2 named W-buffers (1-step, L2).
#define LDA(B, t) { const int off = (t) * 32; \
  B##0 = *(const float4*)(xr0 + off); B##1 = *(const float4*)(xr0 + off + 4); \
  B##2 = *(const float4*)(xr1 + off); B##3 = *(const float4*)(xr1 + off + 4); }
#define LDW(B, t) { B##0 = wfp[((t) * 4 + 0) * 64]; B##1 = wfp[((t) * 4 + 1) * 64]; \
                    B##2 = wfp[((t) * 4 + 2) * 64]; B##3 = wfp[((t) * 4 + 3) * 64]; }
#define STEP(A, W) { f16x8 am0 = cvt8(A##0, A##1); f16x8 am1 = cvt8(A##2, A##3); \
  acc00 = __builtin_amdgcn_mfma_f32_16x16x32_f16(am0, W##0, acc00, 0, 0, 0); \
  acc10 = __builtin_amdgcn_mfma_f32_16x16x32_f16(am1, W##0, acc10, 0, 0, 0); \
  acc01 = __builtin_amdgcn_mfma_f32_16x16x32_f16(am0, W##1, acc01, 0, 0, 0); \
  acc11 = __builtin_amdgcn_mfma_f32_16x16x32_f16(am1, W##1, acc11, 0, 0, 0); \
  acc02 = __builtin_amdgcn_mfma_f32_16x16x32_f16(am0, W##2, acc02, 0, 0, 0); \
  acc12 = __builtin_amdgcn_mfma_f32_16x16x32_f16(am1, W##2, acc12, 0, 0, 0); \
  acc03 = __builtin_amdgcn_mfma_f32_16x16x32_f16(am0, W##3, acc03, 0, 0, 0); \
  acc13 = __builtin_amdgcn_mfma_f32_16x16x32_f16(am1, W##3, acc13, 0, 0, 0); }

__global__ __launch_bounds__(256, 3) void k_gemm1m(const float* __restrict__ x, const _Float16* __restrict__ wf,
                                                   const float* __restrict__ dinv, __half* __restrict__ h1, int n) {
  const int tid = threadIdx.x;
  const int lane = tid & 63;
  const int wv = tid >> 6;
  const int n0 = blockIdx.x * 128 + wv * 32;
  const int kg = lane >> 4;  // 0..3 (k-group)
  const int rr = lane & 15;  // row-in-tile / col-in-tile

  const float* xr0 = x + (size_t)min(n0 + rr, n - 1) * 512 + kg * 8;
  const float* xr1 = x + (size_t)min(n0 + 16 + rr, n - 1) * 512 + kg * 8;
  const f16x8* wfp = (const f16x8*)wf + lane;

  auto cvt8 = [&](const float4& lo, const float4& hi) -> f16x8 {
    f16x8 r;
    r[0] = (_Float16)lo.x; r[1] = (_Float16)lo.y; r[2] = (_Float16)lo.z; r[3] = (_Float16)lo.w;
    r[4] = (_Float16)hi.x; r[5] = (_Float16)hi.y; r[6] = (_Float16)hi.z; r[7] = (_Float16)hi.w;
    return r;
  };

  float4 p0, p1, p2, p3, q0, q1, q2, q3, r0, r1, r2, r3, s0, s1, s2, s3;
  f16x8 u0, u1, u2, u3, v0, v1, v2, v3;
  f32x4 acc00 = {0,0,0,0}, acc01 = {0,0,0,0}, acc02 = {0,0,0,0}, acc03 = {0,0,0,0};
  f32x4 acc10 = {0,0,0,0}, acc11 = {0,0,0,0}, acc12 = {0,0,0,0}, acc13 = {0,0,0,0};

  // prologue: A for steps 0,1 in flight; W for steps 0,1
  LDA(p, 0); LDA(q, 1); LDW(u, 0); LDW(v, 1);
  // steady state: A loaded 2 steps ahead, W 1 step ahead (after its consumer)
  for (int t = 0; t < 12; t += 4) {
    LDA(r, t + 2); STEP(p, u); LDW(u, t + 2);
    LDA(s, t + 3); STEP(q, v); LDW(v, t + 3);
    LDA(p, t + 4); STEP(r, u); LDW(u, t + 4);
    LDA(q, t + 5); STEP(s, v); LDW(v, t + 5);
  }
  // tail: P=A(12), Q=A(13), U=W(12), V=W(13)
  LDA(r, 14); STEP(p, u); LDW(u, 14);
  LDA(s, 15); STEP(q, v); LDW(v, 15);
  STEP(r, u);
  STEP(s, v);

  // D layout: node-sub-row = kg*4 + r, feat-col = rr (per 16x16 tile)
#pragma unroll
  for (int r = 0; r < 4; ++r) {
    int node = n0 + kg * 4 + r;
    if (node < n) {
      float di = dinv[node];
      h1[(size_t)node * 64 + 0 * 16 + rr] = __float2half_rn(di * acc00[r]);
      h1[(size_t)node * 64 + 1 * 16 + rr] = __float2half_rn(di * acc01[r]);
      h1[(size_t)node * 64 + 2 * 16 + rr] = __float2half_rn(di * acc02[r]);
      h1[(size_t)node * 64 + 3 * 16 + rr] = __float2half_rn(di * acc03[r]);
    }
  }
#pragma unroll
  for (int r = 0; r < 4; ++r) {
    int node = n0 + 16 + kg * 4 + r;
    if (node < n) {
      float di = dinv[node];
      h1[(size_t)node * 64 + 0 * 16 + rr] = __float2half_rn(di * acc10[r]);
      h1[(size_t)node * 64 + 1 * 16 + rr] = __float2half_rn(di * acc11[r]);
      h1[(size_t)node * 64 + 2 * 16 + rr] = __float2half_rn(di * acc12[r]);
      h1[(size_t)node * 64 + 3 * 16 + rr] = __float2half_rn(di * acc13[r]);
    }
  }
}

// ---------------- bucket-size scan (one block) ----------------
__global__ __launch_bounds__(1024) void k_bscan(const int* __restrict__ bcnt, int* __restrict__ bbase,
                                                int* __restrict__ offs, int NB, int n, int E) {
  __shared__ int sc[1024];
  int tid = threadIdx.x;
  int v = (tid < NB) ? bcnt[tid * 16] : 0;
  sc[tid] = v;
  __syncthreads();
  for (int d = 1; d < 1024; d <<= 1) {
    int t = (tid >= d) ? sc[tid - d] : 0;
    __syncthreads();
    if (tid >= d) sc[tid] += t;
    __syncthreads();
  }
  if (tid < NB) bbase[tid] = sc[tid] - v;  // exclusive
  if (tid == 0) offs[n] = E;
}

// ---------------- per-bucket CSR finalize (also emits offs + dinv) -----------
// Rank captured from the count-pass atomicAdd (pass 2 is atomic-free).
__global__ __launch_bounds__(1024) void k_p2(const int* __restrict__ pairs, const int* __restrict__ bcnt,
                                             const int* __restrict__ bbase, int* __restrict__ offs,
                                             float* __restrict__ dinv, int* __restrict__ csr, int n) {
  __shared__ int lcnt[BPB];
  __shared__ int excl[BPB];
  __shared__ int sbuf[CAP];
  const int tid = threadIdx.x;
  const int b = blockIdx.x;
  const int size = bcnt[b * 16];
  const int base = bbase[b];
  const int node0 = b << BSHIFT;
  const int nb = min(BPB, n - node0);

  if (tid < BPB) lcnt[tid] = 0;
  __syncthreads();

  int stash[6];
  int rank[6];
  int ns = 0;
  for (int i = tid; i < size; i += 1024) {
    int w = pairs[(size_t)b * CAP + i];
    stash[ns] = w;
    rank[ns] = atomicAdd(&lcnt[w & (BPB - 1)], 1);  // rank = old count
    ns++;
  }
  __syncthreads();
  __shared__ int scanv[BPB];
  if (tid < BPB) scanv[tid] = lcnt[tid];
  __syncthreads();
#pragma unroll
  for (int d = 1; d < BPB; d <<= 1) {
    int t = (tid < BPB && tid >= d) ? scanv[tid - d] : 0;
    __syncthreads();
    if (tid < BPB && tid >= d) scanv[tid] += t;
    __syncthreads();
  }
  if (tid < BPB) excl[tid] = scanv[tid] - lcnt[tid];
  if (tid < nb) {
    offs[node0 + tid] = base + (scanv[tid] - lcnt[tid]);
    dinv[node0 + tid] = rsqrtf((float)(lcnt[tid] + 1));  // +1 self-loop
  }
  __syncthreads();
  for (int j = 0; j < ns; ++j) {
    int w = stash[j];
    sbuf[excl[w & (BPB - 1)] + rank[j]] = w >> BSHIFT;
  }
  __syncthreads();
  for (int i = tid; i < size; i += 1024) csr[base + i] = sbuf[i];
}

// ---------------- pull64 (prescaled fp16, 4 edges/instr, csr pipelined) ------
__global__ __launch_bounds__(256) void k_pull64(const __half* __restrict__ h, const int* __restrict__ offs,
                                                const int* __restrict__ csr, const float* __restrict__ dinv,
                                                const float* __restrict__ b1, const float* __restrict__ W2,
                                                float* __restrict__ h2, int n) {
  __shared__ float sa[4][65];
  __shared__ float w2s[512];
  const int tid = threadIdx.x;
  w2s[tid] = W2[tid];
  w2s[tid + 256] = W2[tid + 256];
  const int lane = tid & 63;
  const int wv = tid >> 6;
  const int node = blockIdx.x * 4 + wv;
  const int q = lane >> 4;    // edge slot 0..3
  const int f8 = lane & 15;   // 8B chunk: feats f8*4 .. +3
  const uint2* hp = (const uint2*)h;  // row = 16 uint2
  float ax = 0.f, ay = 0.f, az = 0.f, aw = 0.f;
  if (node < n) {
    const int s0 = offs[node], s1 = offs[node + 1];
    const int cnt = s1 - s0;
    auto acc1 = [&](int src) {
      uint2 vv = hp[(size_t)src * 16 + f8];
      __half2 h0 = *(__half2*)&vv.x;
      __half2 h1v = *(__half2*)&vv.y;
      float2 f0 = __half22float2(h0);
      float2 f1 = __half22float2(h1v);
      ax += f0.x; ay += f0.y; az += f1.x; aw += f1.y;
    };
    if (q == 0) acc1(node);  // self-loop: independent gather, issue first
    int base = 0;
    if (base + 16 <= cnt) {  // pipelined 16-edge groups (csr one group ahead)
      int e = s0 + q;
      int i0 = csr[e], i1 = csr[e + 4], i2 = csr[e + 8], i3 = csr[e + 12];
      for (; base + 32 <= cnt; base += 16) {
        int e2 = s0 + base + 16 + q;
        int j0 = csr[e2], j1 = csr[e2 + 4], j2 = csr[e2 + 8], j3 = csr[e2 + 12];
        acc1(i0); acc1(i1); acc1(i2); acc1(i3);
        i0 = j0; i1 = j1; i2 = j2; i3 = j3;
      }
      acc1(i0); acc1(i1); acc1(i2); acc1(i3);
      base += 16;
    }
    for (; base + 4 <= cnt; base += 4) acc1(csr[s0 + base + q]);
    if (base + q < cnt) acc1(csr[s0 + base + q]);  // tail 0..3
  }
  ax += __shfl_down(ax, 32); ay += __shfl_down(ay, 32);
  az += __shfl_down(az, 32); aw += __shfl_down(aw, 32);
  ax += __shfl_down(ax, 16); ay += __shfl_down(ay, 16);
  az += __shfl_down(az, 16); aw += __shfl_down(aw, 16);
  if (node < n && lane < 16) {
    float di = dinv[node];
    float4 bb = *(const float4*)(b1 + 4 * f8);
    sa[wv][4 * f8 + 0] = fmaxf(fmaf(di, ax, bb.x), 0.f);
    sa[wv][4 * f8 + 1] = fmaxf(fmaf(di, ay, bb.y), 0.f);
    sa[wv][4 * f8 + 2] = fmaxf(fmaf(di, az, bb.z), 0.f);
    sa[wv][4 * f8 + 3] = fmaxf(fmaf(di, aw, bb.w), 0.f);
  }
  __syncthreads();
  if (tid < 32) {
    int j = tid >> 3, f = tid & 7;
    int nd = blockIdx.x * 4 + j;
    if (nd < n) {
      float s = 0.f;
#pragma unroll
      for (int l = 0; l < 64; ++l) s = fmaf(sa[j][l], w2s[l * 8 + f], s);
      h2[(size_t)nd * 8 + f] = dinv[nd] * s;  // prescale for pull8
    }
  }
}

// ---------------- pull8 (prescaled, 2 chains) + fused gemm3 ----------------
__global__ __launch_bounds__(256) void k_pull8(const float* __restrict__ h, const int* __restrict__ offs,
                                               const int* __restrict__ csr, const float* __restrict__ dinv,
                                               const float* __restrict__ b2, const float* __restrict__ W3,
                                               float* __restrict__ h3, int n) {
  __shared__ float sa[4][8];
  __shared__ float w3s[32];
  const int tid = threadIdx.x;
  if (tid < 32) w3s[tid] = W3[tid];
  const int lane = tid & 63;
  const int wv = tid >> 6;
  const int node = blockIdx.x * 4 + wv;
  const int j8 = lane >> 3, f = lane & 7;
  float pa = 0.f, pb = 0.f;
  if (node < n) {
    int s0 = offs[node], s1 = offs[node + 1];
    int e0 = s0;
    for (; e0 + 16 <= s1; e0 += 16) {  // 2 independent gather chains
      int sA = csr[e0 + j8], sB = csr[e0 + 8 + j8];
      pa += h[(size_t)sA * 8 + f];
      pb += h[(size_t)sB * 8 + f];
    }
    for (; e0 < s1; e0 += 8) {
      int e = e0 + j8;
      if (e < s1) pa += h[(size_t)csr[e] * 8 + f];
    }
  }
  float pacc = pa + pb;
  pacc += __shfl_down(pacc, 32);
  pacc += __shfl_down(pacc, 16);
  pacc += __shfl_down(pacc, 8);
  if (node < n && lane < 8) {
    float v = pacc + h[(size_t)node * 8 + f];  // self-loop (prescaled)
    sa[wv][f] = fmaxf(fmaf(dinv[node], v, b2[f]), 0.f);
  }
  __syncthreads();
  if (tid < 16) {
    int j = tid >> 2, ff = tid & 3;
    int nd = blockIdx.x * 4 + j;
    if (nd < n) {
      float s = 0.f;
#pragma unroll
      for (int k = 0; k < 8; ++k) s = fmaf(sa[j][k], w3s[k * 4 + ff], s);
      h3[(size_t)nd * 4 + ff] = dinv[nd] * s;  // prescale for pull4
    }
  }
}

// ---------------- pull4 (prescaled h3 -> prescaled a3, 2 chains) -------------
__global__ __launch_bounds__(256) void k_pull4(const float* __restrict__ h, const int* __restrict__ offs,
                                               const int* __restrict__ csr, const float* __restrict__ dinv,
                                               const float* __restrict__ b3, float* __restrict__ out, int n) {
  const int tid = threadIdx.x;
  const int lane = tid & 63;
  const int node = blockIdx.x * 4 + (tid >> 6);
  if (node >= n) return;
  const int j16 = lane >> 2, f = lane & 3;
  int s0 = offs[node], s1 = offs[node + 1];
  float pa = 0.f, pb = 0.f;
  int e0 = s0;
  for (; e0 + 32 <= s1; e0 += 32) {  // 2 independent gather chains
    int sA = csr[e0 + j16], sB = csr[e0 + 16 + j16];
    pa += h[(size_t)sA * 4 + f];
    pb += h[(size_t)sB * 4 + f];
  }
  for (; e0 < s1; e0 += 16) {
    int e = e0 + j16;
    if (e < s1) pa += h[(size_t)csr[e] * 4 + f];
  }
  float pacc = pa + pb;
  pacc += __shfl_down(pacc, 32);
  pacc += __shfl_down(pacc, 16);
  pacc += __shfl_down(pacc, 8);
  pacc += __shfl_down(pacc, 4);
  if (lane < 4) {
    float di = dinv[node];
    float v = pacc + h[(size_t)node * 4 + f];  // self-loop (prescaled)
    out[(size_t)node * 4 + f] = di * fmaxf(fmaf(di, v, b3[f]), 0.f);  // prescale for pull4o
  }
}

// ---------------- final pull4 (prescaled a3, 2 chains) + fused mu/lv heads ---
__global__ __launch_bounds__(256) void k_pull4o(const float* __restrict__ a3, const int* __restrict__ offs,
                                                const int* __restrict__ csr, const float* __restrict__ dinv,
                                                const float* __restrict__ Wmu, const float* __restrict__ bmu,
                                                const float* __restrict__ Wlv, const float* __restrict__ blv,
                                                float* __restrict__ outp, int n) {
  __shared__ float sg[4][4];
  const int tid = threadIdx.x;
  const int lane = tid & 63;
  const int wv = tid >> 6;
  const int node = blockIdx.x * 4 + wv;
  const int j16 = lane >> 2, f = lane & 3;
  float pa = 0.f, pb = 0.f;
  if (node < n) {
    int s0 = offs[node], s1 = offs[node + 1];
    int e0 = s0;
    for (; e0 + 32 <= s1; e0 += 32) {
      int sA = csr[e0 + j16], sB = csr[e0 + 16 + j16];
      pa += a3[(size_t)sA * 4 + f];
      pb += a3[(size_t)sB * 4 + f];
    }
    for (; e0 < s1; e0 += 16) {
      int e = e0 + j16;
      if (e < s1) pa += a3[(size_t)csr[e] * 4 + f];
    }
  }
  float pacc = pa + pb;
  pacc += __shfl_down(pacc, 32);
  pacc += __shfl_down(pacc, 16);
  pacc += __shfl_down(pacc, 8);
  pacc += __shfl_down(pacc, 4);
  if (node < n && lane < 4) {
    float v = pacc + a3[(size_t)node * 4 + f];  // self-loop (prescaled)
    sg[wv][f] = dinv[node] * v;
  }
  __syncthreads();
  if (tid < 16) {
    int j = tid >> 2, c = tid & 3;  // c: 0=mu0 1=mu1 2=lv0 3=lv1
    int nd = blockIdx.x * 4 + j;
    if (nd < n) {
      const float* Wp = (c < 2) ? Wmu : Wlv;
      const float* bp = (c < 2) ? bmu : blv;
      int cc = c & 1;
      float s = bp[cc];
#pragma unroll
      for (int k = 0; k < 4; ++k) s = fmaf(sg[j][k], Wp[k * 2 + cc], s);
      size_t base = (c < 2) ? 0 : (size_t)2 * n;
      outp[base + (size_t)nd * 2 + cc] = s;
    }
  }
}

extern "C" void kernel_launch(void* const* d_in, const int* in_sizes, int n_in,
                              void* d_out, int out_size, void* d_ws, size_t ws_size,
                              hipStream_t stream) {
  const float* x = (const float*)d_in[0];
  const int* ei = (const int*)d_in[1];
  const float* W1 = (const float*)d_in[2];
  const float* b1 = (const float*)d_in[3];
  const float* W2 = (const float*)d_in[4];
  const float* b2 = (const float*)d_in[5];
  const float* W3 = (const float*)d_in[6];
  const float* b3 = (const float*)d_in[7];
  const float* Wmu = (const float*)d_in[8];
  const float* bmu = (const float*)d_in[9];
  const float* Wlv = (const float*)d_in[10];
  const float* blv = (const float*)d_in[11];
  float* out = (float*)d_out;

  const int N = in_sizes[0] / 512;
  const int E = in_sizes[1] / 2;
  const int* esrc = ei;
  const int* edst = ei + E;
  const int NB = (N + BPB - 1) >> BSHIFT;  // 782

  char* w = (char*)d_ws;
  size_t p = 0;
  auto alloc = [&](size_t bytes) -> void* {
    void* r = w + p;
    p = (p + bytes + 255) & ~(size_t)255;
    return r;
  };
  int* bcnt = (int*)alloc((size_t)NB * 16 * 4);  // 64B-padded counters
  int* bbase = (int*)alloc((size_t)NB * 4);
  int* offs = (int*)alloc((size_t)(N + 1) * 4);
  float* dinv = (float*)alloc((size_t)N * 4);
  int* csr = (int*)alloc((size_t)E * 4);
  int* pairs = (int*)alloc((size_t)NB * CAP * 4);
  __half* h1 = (__half*)alloc((size_t)N * 64 * 2);
  float* h2 = (float*)alloc((size_t)N * 8 * 4);
  float* h3 = (float*)alloc((size_t)N * 4 * 4);
  float* a3 = (float*)alloc((size_t)N * 4 * 4);
  _Float16* wf = (_Float16*)alloc((size_t)512 * 64 * 2);  // W1 fp16 frag layout

  hipMemsetAsync(bcnt, 0, (size_t)NB * 16 * 4, stream);

  k_wprep<<<16, 256, 0, stream>>>(W1, wf);
  k_part<<<256, 1024, 0, stream>>>(esrc, edst, bcnt, pairs, E, NB, 256);
  k_bscan<<<1, 1024, 0, stream>>>(bcnt, bbase, offs, NB, N, E);
  k_p2<<<NB, 1024, 0, stream>>>(pairs, bcnt, bbase, offs, dinv, csr, N);
  k_gemm1m<<<(N + 127) / 128, 256, 0, stream>>>(x, wf, dinv, h1, N);  // after p2: dinv prescale

  k_pull64<<<(N + 3) / 4, 256, 0, stream>>>(h1, offs, csr, dinv, b1, W2, h2, N);
  k_pull8<<<(N + 3) / 4, 256, 0, stream>>>(h2, offs, csr, dinv, b2, W3, h3, N);
  k_pull4<<<(N + 3) / 4, 256, 0, stream>>>(h3, offs, csr, dinv, b3, a3, N);
  k_pull4o<<<(N + 3) / 4, 256, 0, stream>>>(a3, offs, csr, dinv, Wmu, bmu, Wlv, blv, out, N);
}